// Round 7
// baseline (149.521 us; speedup 1.0000x reference)
//
#include <hip/hip_runtime.h>
#include <hip/hip_cooperative_groups.h>

namespace cg = cooperative_groups;

#define Bz 4
#define Nn 1024
#define Cc 23
#define Hh 100
#define KNOTS 257            // v = r/1.5 tabulated on [0,3], 256 cells
#define DSTRIDE 264          // floats per D row (257 padded, 1056B)

// ws float offsets
#define D_OFF     0                 // [4096][264] = 1081344
#define G4_OFF    1081344           // [4096][4] = 16384
#define BIAS_OFF  1097728           // [4]
#define CONV_OFF  1097732           // [4][1024] = 4096 (atomic accumulator)

#define NTILES 512                  // conv tiles: z(4) x aq(4) x s(32)
#define NUNITS 344                  // phase-0 work units

// ---------------------------------------------------------------------------
// Single cooperative kernel. Phase 0: radial-table dgemm + geom4 + bias +
// conv zeroing. grid.sync. Phase 1: all-pairs lerp conv (atomicAdd).
// grid.sync. Phase 2: block 0 computes fc1->fc2->fc3 head.
// ---------------------------------------------------------------------------
__global__ __launch_bounds__(256, 2)
void fused_kernel(const float* __restrict__ f,
                  const float* __restrict__ geom,
                  const float* __restrict__ W1,
                  const float* __restrict__ b1,
                  const float* __restrict__ W2,
                  const float* __restrict__ b2,
                  const float* __restrict__ Wf1, const float* __restrict__ bf1,
                  const float* __restrict__ Wf2, const float* __restrict__ bf2,
                  const float* __restrict__ Wf3, const float* __restrict__ bf3,
                  float* __restrict__ ws,
                  float* __restrict__ out) {
    __shared__ float4 smem4[32 * DSTRIDE / 4];   // 33792 B, aliased per phase
    float* smem = reinterpret_cast<float*>(smem4);
    cg::grid_group grid = cg::this_grid();
    const int bid = blockIdx.x;
    const int G = gridDim.x;
    const int t = threadIdx.x;
    const int lane = t & 63;
    const int wv = __builtin_amdgcn_readfirstlane(t >> 6);

    // ===================== phase 0 =====================
    for (int u = bid; u < NUNITS; u += G) {
        __syncthreads();
        if (u < 320) {
            // dgemm unit: kg = u%5 -> 64 knots (lane=knot), zc = u/5 -> 64 zb rows
            int kg = u % 5, zc = u / 5;
            int k = kg * 64 + lane;
            float v = (float)k * (3.0f / 256.0f);
            const float HPI = 1.57079632679f;
            float c0 = cosf(HPI * v);
            float c1 = cosf(HPI * (v - 1.0f));
            float c2 = cosf(HPI * (v - 2.0f));
            float s0 = (v < 1.0f) ? c0 * c0 : 0.0f;
            float s1 = (fabsf(v - 1.0f) < 1.0f) ? c1 * c1 : 0.0f;
            float s2 = (fabsf(v - 2.0f) < 1.0f) ? c2 * c2 : 0.0f;
            float uacc[Cc];
            #pragma unroll
            for (int c = 0; c < Cc; ++c) uacc[c] = 0.f;
            int h0 = wv * 25;
            #pragma unroll 5
            for (int h = h0; h < h0 + 25; ++h) {
                float hh = fmaxf(fmaf(s0, W1[h],
                                  fmaf(s1, W1[Hh + h],
                                   fmaf(s2, W1[2 * Hh + h], b1[h]))), 0.f);
                #pragma unroll
                for (int c = 0; c < Cc; ++c)
                    uacc[c] = fmaf(hh, W2[h * Cc + c], uacc[c]);
            }
            // h-split partials in LDS: up[wv][lane][25] (stride 25: conflict-free)
            #pragma unroll
            for (int c = 0; c < Cc; ++c) smem[(wv * 64 + lane) * 25 + c] = uacc[c];
            __syncthreads();
            float ur[Cc];
            #pragma unroll
            for (int c = 0; c < Cc; ++c)
                ur[c] = (smem[(0 * 64 + lane) * 25 + c] + smem[(1 * 64 + lane) * 25 + c])
                      + (smem[(2 * 64 + lane) * 25 + c] + smem[(3 * 64 + lane) * 25 + c]);
            int zb0 = zc * 64 + wv * 16;
            float* Dp = ws + D_OFF;
            bool act = k < KNOTS;
            #pragma unroll 4
            for (int i = 0; i < 16; ++i) {
                const float* frow = f + (zb0 + i) * Cc;     // wave-uniform -> s_load
                float a0 = 0.f, a1 = 0.f, a2 = 0.f, a3 = 0.f;
                #pragma unroll
                for (int c = 0; c < 20; c += 4) {
                    a0 = fmaf(frow[c + 0], ur[c + 0], a0);
                    a1 = fmaf(frow[c + 1], ur[c + 1], a1);
                    a2 = fmaf(frow[c + 2], ur[c + 2], a2);
                    a3 = fmaf(frow[c + 3], ur[c + 3], a3);
                }
                a0 = fmaf(frow[20], ur[20], a0);
                a1 = fmaf(frow[21], ur[21], a1);
                a2 = fmaf(frow[22], ur[22], a2);
                if (act) Dp[(zb0 + i) * DSTRIDE + k] = (a0 + a1) + (a2 + a3);
            }
        } else if (u < 336) {                 // geom4 pack
            int zb = (u - 320) * 256 + t;
            const float* g = geom + zb * 3;
            reinterpret_cast<float4*>(ws + G4_OFF)[zb] =
                make_float4(g[0], g[1], g[2], 0.f);
        } else if (u < 340) {                 // bias[z]
            int z = u - 336;
            float s = 0.f;
            for (int b = t; b < Nn; b += 256) {
                const float* frow = f + (z * Nn + b) * Cc;
                #pragma unroll
                for (int c = 0; c < Cc; ++c) s = fmaf(frow[c], b2[c], s);
            }
            smem[t] = s; __syncthreads();
            for (int off = 128; off; off >>= 1) {
                if (t < off) smem[t] += smem[t + off];
                __syncthreads();
            }
            if (t == 0) ws[BIAS_OFF + z] = smem[0];
        } else {                              // zero conv accumulator (agent-scope)
            int base = (u - 340) * 1024;
            #pragma unroll
            for (int j = 0; j < 4; ++j)
                __hip_atomic_store(&ws[CONV_OFF + base + j * 256 + t], 0.f,
                                   __ATOMIC_RELAXED, __HIP_MEMORY_SCOPE_AGENT);
        }
    }

    grid.sync();

    // ===================== phase 1: conv =====================
    const float4* geom4 = reinterpret_cast<const float4*>(ws + G4_OFF);
    for (int tile = bid; tile < NTILES; tile += G) {
        __syncthreads();
        int s = tile & 31;
        int aq = (tile >> 5) & 3;
        int z = tile >> 7;
        int b0 = s * 32;
        const float4* src = reinterpret_cast<const float4*>(ws + D_OFF + (z * Nn + b0) * DSTRIDE);
        for (int j = t; j < 32 * DSTRIDE / 4; j += 256) smem4[j] = src[j];
        float4 ga = geom4[z * Nn + aq * 256 + t];
        __syncthreads();
        float acc = 0.f;
        #pragma unroll 8
        for (int bl = 0; bl < 32; ++bl) {
            float4 gb = geom4[z * Nn + b0 + bl];          // uniform -> scalar load
            float dx = ga.x - gb.x, dy = ga.y - gb.y, dz = ga.z - gb.z;
            float r = sqrtf(fmaf(dx, dx, fmaf(dy, dy, fmaf(dz, dz, 1e-12f))));
            float mu = fminf(r * 56.8888889f, 255.999f);  // v*256/3, clamped
            int m = (int)mu;
            float tt = mu - (float)m;
            const float* row = smem + bl * DSTRIDE + m;
            float d0 = row[0];
            float d1 = row[1];
            acc += fmaf(tt, d1 - d0, d0);
        }
        atomicAdd(&ws[CONV_OFF + (z << 10) + aq * 256 + t], acc);
    }

    grid.sync();

    // ===================== phase 2: head (block 0) =====================
    if (bid == 0) {
        float* r2  = smem;          // [120][2]
        float* x1s = smem + 240;    // [120]
        float* x2s = smem + 368;    // [40]
        __syncthreads();
        if (t < 240) {
            int p = t >> 1, half = t & 1;
            int z = p / 30, d = p % 30;
            float biasz = ws[BIAS_OFF + z];
            const float* cz = ws + CONV_OFF + (z << 10);
            float acc = 0.f;
            int k0 = half * 512;
            #pragma unroll 4
            for (int i = 0; i < 512; ++i) {
                int k = k0 + i;
                float x = (cz[k] + biasz) * 0.03125f;
                acc = fmaf(x, Wf1[k * 30 + d], acc);
            }
            r2[p * 2 + half] = acc;
        }
        __syncthreads();
        if (t < 120)
            x1s[t] = fmaxf(r2[t * 2] + r2[t * 2 + 1] + bf1[t % 30], 0.f);
        __syncthreads();
        if (t < 40) {
            int z = t / 10, d = t % 10;
            float s = bf2[d];
            #pragma unroll
            for (int kk = 0; kk < 30; ++kk)
                s = fmaf(x1s[z * 30 + kk], Wf2[kk * 10 + d], s);
            x2s[t] = fmaxf(s, 0.f);
        }
        __syncthreads();
        if (t < Bz) {
            float s = bf3[0];
            #pragma unroll
            for (int kk = 0; kk < 10; ++kk)
                s = fmaf(x2s[t * 10 + kk], Wf3[kk], s);
            out[t] = s;
        }
    }
}

extern "C" void kernel_launch(void* const* d_in, const int* in_sizes, int n_in,
                              void* d_out, int out_size, void* d_ws, size_t ws_size,
                              hipStream_t stream) {
    const float* f   = (const float*)d_in[0];
    const float* geo = (const float*)d_in[1];
    const float* W1  = (const float*)d_in[2];
    const float* b1  = (const float*)d_in[3];
    const float* W2  = (const float*)d_in[4];
    const float* b2  = (const float*)d_in[5];
    const float* Wf1 = (const float*)d_in[6];
    const float* bf1 = (const float*)d_in[7];
    const float* Wf2 = (const float*)d_in[8];
    const float* bf2 = (const float*)d_in[9];
    const float* Wf3 = (const float*)d_in[10];
    const float* bf3 = (const float*)d_in[11];
    float* ws  = (float*)d_ws;
    float* out = (float*)d_out;

    // occupancy-bounded cooperative grid (host-only queries; capture-safe)
    int perCU = 0, nCU = 0, dev = 0;
    hipGetDevice(&dev);
    hipOccupancyMaxActiveBlocksPerMultiprocessor(&perCU, (const void*)fused_kernel, 256, 0);
    hipDeviceGetAttribute(&nCU, hipDeviceAttributeMultiprocessorCount, dev);
    if (perCU < 1) perCU = 1;
    if (nCU <= 0) nCU = 256;
    int G = perCU * nCU;
    if (G > NTILES) G = NTILES;

    void* args[] = { (void*)&f, (void*)&geo, (void*)&W1, (void*)&b1, (void*)&W2,
                     (void*)&b2, (void*)&Wf1, (void*)&bf1, (void*)&Wf2, (void*)&bf2,
                     (void*)&Wf3, (void*)&bf3, (void*)&ws, (void*)&out };
    hipLaunchCooperativeKernel((void*)fused_kernel, dim3(G), dim3(256), args, 0, stream);
}

// Round 8
// 81.825 us; speedup vs baseline: 1.8273x; 1.8273x over previous
//
#include <hip/hip_runtime.h>

#define Bz 4
#define Nn 1024
#define Cc 23
#define Hh 100
#define KNOTS 257            // v = r/1.5 tabulated on [0,3], 256 cells
#define DSTRIDE 264          // floats per D row (257 padded)

// ws float offsets
#define D_OFF     0                 // [4096][264] = 1081344
#define G4_OFF    1081344           // [4096][4] = 16384
#define BIAS_OFF  1097728           // [4]
#define CONV_OFF  1097732           // [4][1024] = 4096 (atomic accumulator)
#define X1_OFF    1101828           // [120]
#define CTR_OFF   1101952           // 16 uints (64B-aligned), zeroed by memset node

#define NBLOCKS 512
#define NUNITS  344
#define SCOPE __HIP_MEMORY_SCOPE_AGENT

__device__ __forceinline__ void arrive(unsigned* c) {
    __hip_atomic_fetch_add(c, 1u, __ATOMIC_RELEASE, SCOPE);
}
__device__ __forceinline__ void spin_until(unsigned* c, unsigned target) {
    while (__hip_atomic_load(c, __ATOMIC_RELAXED, SCOPE) < target)
        __builtin_amdgcn_s_sleep(2);
    (void)__hip_atomic_load(c, __ATOMIC_ACQUIRE, SCOPE);   // inv L1/L2
}

// ---------------------------------------------------------------------------
// One kernel, 512 blocks x 256 threads (2/CU guaranteed resident).
//  stage 0 (bid<344): dgemm units / geom4 / bias / conv-zero  -> ticket c0
//  all blocks spin c0==512 (acquire)
//  stage 1: conv tile = bid (lerp gather, atomicAdd)          -> ticket c1
//  blocks 0..119 spin c1==512, compute fc1 pair (z,d)=bid     -> ticket c2
//  last fc1 block runs fc2+fc3 inline, writes out[4]
// ---------------------------------------------------------------------------
__global__ __launch_bounds__(256, 2)
void mega_kernel(const float* __restrict__ f,
                 const float* __restrict__ geom,
                 const float* __restrict__ W1,
                 const float* __restrict__ b1,
                 const float* __restrict__ W2,
                 const float* __restrict__ b2,
                 const float* __restrict__ Wf1, const float* __restrict__ bf1,
                 const float* __restrict__ Wf2, const float* __restrict__ bf2,
                 const float* __restrict__ Wf3, const float* __restrict__ bf3,
                 float* __restrict__ ws,
                 float* __restrict__ out) {
    __shared__ float4 smem4[32 * DSTRIDE / 4];   // 33792 B
    float* smem = reinterpret_cast<float*>(smem4);
    __shared__ int lastflag;
    unsigned* ctr = reinterpret_cast<unsigned*>(ws + CTR_OFF);
    const int bid = blockIdx.x;
    const int t = threadIdx.x;
    const int lane = t & 63;
    const int wv = __builtin_amdgcn_readfirstlane(t >> 6);

    // ===================== stage 0 =====================
    if (bid < 320) {
        // dgemm unit: kg -> 64 knots (lane=knot), zc -> 64 zb rows (16/wave)
        int kg = bid % 5, zc = bid / 5;
        int k = kg * 64 + lane;
        float v = (float)k * (3.0f / 256.0f);
        const float HPI = 1.57079632679f;
        float c0 = cosf(HPI * v);
        float c1 = cosf(HPI * (v - 1.0f));
        float c2 = cosf(HPI * (v - 2.0f));
        float s0 = (v < 1.0f) ? c0 * c0 : 0.0f;
        float s1 = (fabsf(v - 1.0f) < 1.0f) ? c1 * c1 : 0.0f;
        float s2 = (fabsf(v - 2.0f) < 1.0f) ? c2 * c2 : 0.0f;
        float uacc[Cc];
        #pragma unroll
        for (int c = 0; c < Cc; ++c) uacc[c] = 0.f;
        int h0 = wv * 25;
        #pragma unroll 5
        for (int h = h0; h < h0 + 25; ++h) {
            float hh = fmaxf(fmaf(s0, W1[h],
                              fmaf(s1, W1[Hh + h],
                               fmaf(s2, W1[2 * Hh + h], b1[h]))), 0.f);
            #pragma unroll
            for (int c = 0; c < Cc; ++c)
                uacc[c] = fmaf(hh, W2[h * Cc + c], uacc[c]);
        }
        #pragma unroll
        for (int c = 0; c < Cc; ++c) smem[(wv * 64 + lane) * 25 + c] = uacc[c];
        __syncthreads();
        float ur[Cc];
        #pragma unroll
        for (int c = 0; c < Cc; ++c)
            ur[c] = (smem[(0 * 64 + lane) * 25 + c] + smem[(1 * 64 + lane) * 25 + c])
                  + (smem[(2 * 64 + lane) * 25 + c] + smem[(3 * 64 + lane) * 25 + c]);
        int zb0 = zc * 64 + wv * 16;
        float* Dp = ws + D_OFF;
        bool act = k < KNOTS;
        #pragma unroll 4
        for (int i = 0; i < 16; ++i) {
            const float* frow = f + (zb0 + i) * Cc;     // wave-uniform -> s_load
            float a0 = 0.f, a1 = 0.f, a2 = 0.f, a3 = 0.f;
            #pragma unroll
            for (int c = 0; c < 20; c += 4) {
                a0 = fmaf(frow[c + 0], ur[c + 0], a0);
                a1 = fmaf(frow[c + 1], ur[c + 1], a1);
                a2 = fmaf(frow[c + 2], ur[c + 2], a2);
                a3 = fmaf(frow[c + 3], ur[c + 3], a3);
            }
            a0 = fmaf(frow[20], ur[20], a0);
            a1 = fmaf(frow[21], ur[21], a1);
            a2 = fmaf(frow[22], ur[22], a2);
            if (act) Dp[(zb0 + i) * DSTRIDE + k] = (a0 + a1) + (a2 + a3);
        }
    } else if (bid < 336) {                 // geom4 pack
        int zb = (bid - 320) * 256 + t;
        const float* g = geom + zb * 3;
        reinterpret_cast<float4*>(ws + G4_OFF)[zb] =
            make_float4(g[0], g[1], g[2], 0.f);
    } else if (bid < 340) {                 // bias[z]
        int z = bid - 336;
        float s = 0.f;
        for (int b = t; b < Nn; b += 256) {
            const float* frow = f + (z * Nn + b) * Cc;
            #pragma unroll
            for (int c = 0; c < Cc; ++c) s = fmaf(frow[c], b2[c], s);
        }
        smem[t] = s; __syncthreads();
        for (int off = 128; off; off >>= 1) {
            if (t < off) smem[t] += smem[t + off];
            __syncthreads();
        }
        if (t == 0) ws[BIAS_OFF + z] = smem[0];
    } else if (bid < NUNITS) {              // zero conv accumulator
        int base = (bid - 340) * 1024;
        #pragma unroll
        for (int j = 0; j < 4; ++j)
            ws[CONV_OFF + base + j * 256 + t] = 0.f;
    }
    __syncthreads();
    if (t == 0) {
        arrive(&ctr[0]);
        spin_until(&ctr[0], NBLOCKS);
    }
    __syncthreads();

    // ===================== stage 1: conv =====================
    {
        const float4* geom4 = reinterpret_cast<const float4*>(ws + G4_OFF);
        int s = bid & 31;
        int aq = (bid >> 5) & 3;
        int z = bid >> 7;
        int b0 = s * 32;
        const float4* src = reinterpret_cast<const float4*>(ws + D_OFF + (z * Nn + b0) * DSTRIDE);
        for (int j = t; j < 32 * DSTRIDE / 4; j += 256) smem4[j] = src[j];
        float4 ga = geom4[z * Nn + aq * 256 + t];
        __syncthreads();
        float acc = 0.f;
        #pragma unroll 8
        for (int bl = 0; bl < 32; ++bl) {
            float4 gb = geom4[z * Nn + b0 + bl];          // uniform -> scalar load
            float dx = ga.x - gb.x, dy = ga.y - gb.y, dz = ga.z - gb.z;
            float r = sqrtf(fmaf(dx, dx, fmaf(dy, dy, fmaf(dz, dz, 1e-12f))));
            float mu = fminf(r * 56.8888889f, 255.999f);  // v*256/3, clamped
            int m = (int)mu;
            float tt = mu - (float)m;
            const float* row = smem + bl * DSTRIDE + m;
            float d0 = row[0];
            float d1 = row[1];
            acc += fmaf(tt, d1 - d0, d0);
        }
        atomicAdd(&ws[CONV_OFF + (z << 10) + aq * 256 + t], acc);
    }
    __syncthreads();
    if (t == 0) arrive(&ctr[1]);
    if (bid >= 120) return;

    // ===================== stage 2: fc1 (blocks 0..119) =====================
    if (t == 0) spin_until(&ctr[1], NBLOCKS);
    __syncthreads();
    {
        int z = bid / 30, d = bid % 30;
        float biasz = ws[BIAS_OFF + z];
        const float* cz = ws + CONV_OFF + (z << 10);
        float acc = 0.f;
        #pragma unroll
        for (int i = 0; i < 4; ++i) {
            int k = i * 256 + t;
            float x = (cz[k] + biasz) * 0.03125f;
            acc = fmaf(x, Wf1[k * 30 + d], acc);
        }
        #pragma unroll
        for (int off = 32; off; off >>= 1) acc += __shfl_down(acc, off);
        if (lane == 0) smem[128 + wv] = acc;
        __syncthreads();
        if (t == 0) {
            float s = (smem[128] + smem[129]) + (smem[130] + smem[131]);
            ws[X1_OFF + bid] = fmaxf(s + bf1[d], 0.f);
            unsigned r = __hip_atomic_fetch_add(&ctr[2], 1u, __ATOMIC_RELEASE, SCOPE);
            if (r == 119u)
                (void)__hip_atomic_load(&ctr[2], __ATOMIC_ACQUIRE, SCOPE);
            lastflag = (r == 119u) ? 1 : 0;
        }
    }
    __syncthreads();
    if (!lastflag) return;

    // ===================== stage 3: fc2+fc3 (one block) =====================
    if (t < 40) {
        int z = t / 10, d = t % 10;
        float s = bf2[d];
        #pragma unroll
        for (int kk = 0; kk < 30; ++kk)
            s = fmaf(ws[X1_OFF + z * 30 + kk], Wf2[kk * 10 + d], s);
        smem[200 + t] = fmaxf(s, 0.f);
    }
    __syncthreads();
    if (t < Bz) {
        float s = bf3[0];
        #pragma unroll
        for (int kk = 0; kk < 10; ++kk)
            s = fmaf(smem[200 + t * 10 + kk], Wf3[kk], s);
        out[t] = s;
    }
}

extern "C" void kernel_launch(void* const* d_in, const int* in_sizes, int n_in,
                              void* d_out, int out_size, void* d_ws, size_t ws_size,
                              hipStream_t stream) {
    const float* f   = (const float*)d_in[0];
    const float* geo = (const float*)d_in[1];
    const float* W1  = (const float*)d_in[2];
    const float* b1  = (const float*)d_in[3];
    const float* W2  = (const float*)d_in[4];
    const float* b2  = (const float*)d_in[5];
    const float* Wf1 = (const float*)d_in[6];
    const float* bf1 = (const float*)d_in[7];
    const float* Wf2 = (const float*)d_in[8];
    const float* bf2 = (const float*)d_in[9];
    const float* Wf3 = (const float*)d_in[10];
    const float* bf3 = (const float*)d_in[11];
    float* ws  = (float*)d_ws;
    float* out = (float*)d_out;

    // zero the barrier counters (capture-safe async memset node)
    hipMemsetAsync(ws + CTR_OFF, 0, 64, stream);
    hipLaunchKernelGGL(mega_kernel, dim3(NBLOCKS), dim3(256), 0, stream,
                       f, geo, W1, b1, W2, b2,
                       Wf1, bf1, Wf2, bf2, Wf3, bf3, ws, out);
}

// Round 9
// 52.690 us; speedup vs baseline: 2.8378x; 1.5530x over previous
//
#include <hip/hip_runtime.h>

#define Bz 4
#define Nn 1024
#define Cc 23
#define Hh 100
#define KN 128                 // knots over v=r/1.5 in [0,3], 127 cells
#define DSTR 132               // lds_d row stride (128 + pad)
#define MUSCALE 28.2222222f    // 127/4.5  (mu = r * MUSCALE)
#define MUCLAMP 126.999f

// ws float offsets (tiny now — no global D array)
#define PB_OFF     0           // [30][512] per-block fc1 partials = 15360
#define BIAS_OFF   15360       // [4]
#define COLSUM_OFF 15364       // [30]
#define CTR_OFF    15400       // 1 uint (memset to 0 each call)

#define NBLOCKS 512

// ---------------------------------------------------------------------------
// One kernel, 512 blocks x 256 threads. Block = (z, aq, s): owns a-range
// aq*256..+255 and b-range s*32..+31. No inter-block waiting anywhere:
//   A: recompute radial table U[128][23] cooperatively (redundant per block)
//   B: build D-chunk[32 rows][128 knots] in LDS (rows = its own b's)
//   C: conv lerp-gather, per-thread acc over 32 b's for its a=k
//   D: fold accs through Wf1 -> 30 partials, plain-store to pb[d][bid]
//   ticket fetch_add(ACQ_REL); block drawing 511 computes the head inline.
// ---------------------------------------------------------------------------
__global__ __launch_bounds__(256, 2)
void mega_kernel(const float* __restrict__ f,
                 const float* __restrict__ geom,
                 const float* __restrict__ W1,
                 const float* __restrict__ b1,
                 const float* __restrict__ W2,
                 const float* __restrict__ b2,
                 const float* __restrict__ Wf1, const float* __restrict__ bf1,
                 const float* __restrict__ Wf2, const float* __restrict__ bf2,
                 const float* __restrict__ Wf3, const float* __restrict__ bf3,
                 float* __restrict__ ws,
                 float* __restrict__ out) {
    __shared__ float lds_u[2 * KN * 25];    // 25600 B  (aliased: acc/tail later)
    __shared__ float lds_d[32 * DSTR];      // 16896 B
    __shared__ int   lastflag;
    float* lds_acc  = lds_u;                // [256] fold staging
    float* lds_tail = lds_u + 256;          // tail scratch

    const int bid = blockIdx.x;
    const int t = threadIdx.x;
    const int lane = t & 63;
    const int wv = __builtin_amdgcn_readfirstlane(t >> 6);
    const int z = bid >> 7;
    const int aq = (bid >> 5) & 3;
    const int s = bid & 31;
    const int b0 = s * 32;

    // ============ A: radial table U (128 knots x 23 c), h split in halves ====
    {
        int k = t & 127;
        int hh = __builtin_amdgcn_readfirstlane(t >> 7);   // 0/1
        float v = (float)k * (3.0f / 127.0f);
        const float HPI = 1.57079632679f;
        float c0 = cosf(HPI * v);
        float c1 = cosf(HPI * (v - 1.0f));
        float c2 = cosf(HPI * (v - 2.0f));
        float s0 = (v < 1.0f) ? c0 * c0 : 0.0f;
        float s1 = (fabsf(v - 1.0f) < 1.0f) ? c1 * c1 : 0.0f;
        float s2 = (v > 1.0f && v < 3.0f) ? c2 * c2 : 0.0f;
        float uacc[Cc];
        #pragma unroll
        for (int c = 0; c < Cc; ++c) uacc[c] = 0.f;
        int h0 = hh * 50;
        #pragma unroll 2
        for (int h = h0; h < h0 + 50; ++h) {               // W loads wave-uniform
            float pre = fmaf(s0, W1[h],
                         fmaf(s1, W1[Hh + h],
                          fmaf(s2, W1[2 * Hh + h], b1[h])));
            float hv = fmaxf(pre, 0.f);
            #pragma unroll
            for (int c = 0; c < Cc; ++c)
                uacc[c] = fmaf(hv, W2[h * Cc + c], uacc[c]);
        }
        #pragma unroll
        for (int c = 0; c < Cc; ++c)
            lds_u[(hh * KN + k) * 25 + c] = uacc[c];
    }
    __syncthreads();

    // ============ B: D-chunk rows b0..b0+31 into LDS =========================
    {
        int kk = t & 127;
        int rh = __builtin_amdgcn_readfirstlane(t >> 7);   // row half
        float ur[Cc];
        #pragma unroll
        for (int c = 0; c < Cc; ++c)
            ur[c] = lds_u[kk * 25 + c] + lds_u[(KN + kk) * 25 + c];
        #pragma unroll 2
        for (int i = 0; i < 16; ++i) {
            int row = rh * 16 + i;
            const float* frow = f + ((z << 10) + b0 + row) * Cc;  // uniform -> s_load
            float a0 = 0.f, a1 = 0.f, a2 = 0.f, a3 = 0.f;
            #pragma unroll
            for (int c = 0; c < 20; c += 4) {
                a0 = fmaf(frow[c + 0], ur[c + 0], a0);
                a1 = fmaf(frow[c + 1], ur[c + 1], a1);
                a2 = fmaf(frow[c + 2], ur[c + 2], a2);
                a3 = fmaf(frow[c + 3], ur[c + 3], a3);
            }
            a0 = fmaf(frow[20], ur[20], a0);
            a1 = fmaf(frow[21], ur[21], a1);
            a2 = fmaf(frow[22], ur[22], a2);
            lds_d[row * DSTR + kk] = (a0 + a1) + (a2 + a3);
        }
    }
    __syncthreads();

    // ============ C: conv — thread t owns a = aq*256+t ======================
    float acc = 0.f;
    {
        int ag = (z << 10) + (aq << 8) + t;
        float gax = geom[ag * 3], gay = geom[ag * 3 + 1], gaz = geom[ag * 3 + 2];
        #pragma unroll 8
        for (int bl = 0; bl < 32; ++bl) {
            const float* gb = geom + ((z << 10) + b0 + bl) * 3;   // uniform -> s_load
            float dx = gax - gb[0], dy = gay - gb[1], dz = gaz - gb[2];
            float r = sqrtf(fmaf(dx, dx, fmaf(dy, dy, fmaf(dz, dz, 1e-12f))));
            float mu = fminf(r * MUSCALE, MUCLAMP);
            int m = (int)mu;
            float tt = mu - (float)m;
            const float* row = lds_d + bl * DSTR + m;
            float d0 = row[0];
            float d1 = row[1];
            acc += fmaf(tt, d1 - d0, d0);
        }
    }

    // ============ D: fold accs through Wf1 -> pb[d][bid] ====================
    lds_acc[t] = acc;
    __syncthreads();
    {
        const float4* a4 = reinterpret_cast<const float4*>(lds_acc);
        float4 av = a4[lane];                       // acc for k = 4*lane..+3
        int kbase = (aq << 8) + (lane << 2);
        #pragma unroll
        for (int i = 0; i < 8; ++i) {
            int d = wv + 4 * i;
            if (d < 30) {
                float sum = av.x * Wf1[(kbase + 0) * 30 + d]
                          + av.y * Wf1[(kbase + 1) * 30 + d]
                          + av.z * Wf1[(kbase + 2) * 30 + d]
                          + av.w * Wf1[(kbase + 3) * 30 + d];
                #pragma unroll
                for (int off = 32; off; off >>= 1) sum += __shfl_down(sum, off);
                if (lane == 0) ws[PB_OFF + d * NBLOCKS + bid] = sum * 0.03125f;
            }
        }
    }

    // ============ block 0 extras: bias[z], colsum[d] ========================
    if (bid == 0) {
        // bias: wave wv handles z=wv; lane sums 16 strided rows
        float bs = 0.f;
        for (int j = 0; j < 16; ++j) {
            const float* fr = f + ((wv << 10) + j * 64 + lane) * Cc;
            #pragma unroll
            for (int c = 0; c < Cc; ++c) bs = fmaf(fr[c], b2[c], bs);
        }
        #pragma unroll
        for (int off = 32; off; off >>= 1) bs += __shfl_down(bs, off);
        if (lane == 0) ws[BIAS_OFF + wv] = bs;
        // colsum[d] = sum_k Wf1[k][d], 8 octaves x 30 d
        if (t < 240) {
            int d = t % 30, oct = t / 30;
            float cs = 0.f;
            #pragma unroll 4
            for (int j = 0; j < 128; ++j)
                cs += Wf1[(oct * 128 + j) * 30 + d];
            lds_tail[oct * 30 + d] = cs;
        }
        __syncthreads();
        if (t < 30) {
            float cs = 0.f;
            #pragma unroll
            for (int o = 0; o < 8; ++o) cs += lds_tail[o * 30 + t];
            ws[COLSUM_OFF + t] = cs;
        }
    }

    // ============ ticket: last arriver runs the head ========================
    __syncthreads();
    if (t == 0) {
        unsigned* ctr = reinterpret_cast<unsigned*>(ws + CTR_OFF);
        unsigned r = __hip_atomic_fetch_add(ctr, 1u, __ATOMIC_ACQ_REL,
                                            __HIP_MEMORY_SCOPE_AGENT);
        lastflag = (r == NBLOCKS - 1) ? 1 : 0;
    }
    __syncthreads();
    if (!lastflag) return;

    // -------- head (single block) --------
    {
        int p = t >> 1, half = t & 1;
        if (p < 120) {
            int zz = p / 30, d = p % 30;
            const float* pbp = ws + PB_OFF + d * NBLOCKS + zz * 128 + half * 64;
            float sm = 0.f;
            #pragma unroll 4
            for (int j = 0; j < 64; ++j) sm += pbp[j];
            lds_tail[p * 2 + half] = sm;
        }
    }
    __syncthreads();
    if (t < 120) {
        int zz = t / 30, d = t % 30;
        float x1 = lds_tail[2 * t] + lds_tail[2 * t + 1]
                 + ws[BIAS_OFF + zz] * 0.03125f * ws[COLSUM_OFF + d]
                 + bf1[d];
        lds_tail[256 + t] = fmaxf(x1, 0.f);
    }
    __syncthreads();
    if (t < 40) {
        int zz = t / 10, d = t % 10;
        float sm = bf2[d];
        #pragma unroll
        for (int kk = 0; kk < 30; ++kk)
            sm = fmaf(lds_tail[256 + zz * 30 + kk], Wf2[kk * 10 + d], sm);
        lds_tail[384 + t] = fmaxf(sm, 0.f);
    }
    __syncthreads();
    if (t < Bz) {
        float sm = bf3[0];
        #pragma unroll
        for (int kk = 0; kk < 10; ++kk)
            sm = fmaf(lds_tail[384 + t * 10 + kk], Wf3[kk], sm);
        out[t] = sm;
    }
}

extern "C" void kernel_launch(void* const* d_in, const int* in_sizes, int n_in,
                              void* d_out, int out_size, void* d_ws, size_t ws_size,
                              hipStream_t stream) {
    const float* f   = (const float*)d_in[0];
    const float* geo = (const float*)d_in[1];
    const float* W1  = (const float*)d_in[2];
    const float* b1  = (const float*)d_in[3];
    const float* W2  = (const float*)d_in[4];
    const float* b2  = (const float*)d_in[5];
    const float* Wf1 = (const float*)d_in[6];
    const float* bf1 = (const float*)d_in[7];
    const float* Wf2 = (const float*)d_in[8];
    const float* bf2 = (const float*)d_in[9];
    const float* Wf3 = (const float*)d_in[10];
    const float* bf3 = (const float*)d_in[11];
    float* ws  = (float*)d_ws;
    float* out = (float*)d_out;

    hipMemsetAsync(ws + CTR_OFF, 0, 64, stream);   // zero ticket counter
    hipLaunchKernelGGL(mega_kernel, dim3(NBLOCKS), dim3(256), 0, stream,
                       f, geo, W1, b1, W2, b2,
                       Wf1, bf1, Wf2, bf2, Wf3, bf3, ws, out);
}

// Round 10
// 31.547 us; speedup vs baseline: 4.7396x; 1.6702x over previous
//
#include <hip/hip_runtime.h>

#define Nn 1024
#define Cc 23
#define Hh 100
#define KN 128                 // knots over v=r/1.5 in [0,3], 127 cells
#define DSTR 132               // lds_d row stride (128 + pad)
#define MUSCALE 28.2222222f    // 127/4.5  (mu = r * MUSCALE)
#define MUCLAMP 126.999f
#define NBLOCKS 512

// ws float offsets
#define UT_OFF     0           // U transposed [23][128] = 2944
#define G4_OFF     2944        // [4096][4] = 16384
#define BIAS_OFF   19328       // [4]
#define COLSUM_OFF 19332       // [30]
#define PB_OFF     19392       // [30][512] fc1 partials = 15360

// ---------------------------------------------------------------------------
// K0: radial table U_T[c][k] (128 blocks, per-lane coalesced W loads),
//     geom4 pack (16), bias[z] (4), Wf1 colsum (1).  Grid = 149 blocks.
//     Also warms L2 for f / geom / Wf1 / W2 before K1.
// ---------------------------------------------------------------------------
__global__ __launch_bounds__(256)
void prep_kernel(const float* __restrict__ f,
                 const float* __restrict__ geom,
                 const float* __restrict__ W1,
                 const float* __restrict__ b1,
                 const float* __restrict__ W2,
                 const float* __restrict__ b2,
                 const float* __restrict__ Wf1,
                 float* __restrict__ ws) {
    int blk = blockIdx.x;
    int t = threadIdx.x;
    if (blk < 128) {                       // one knot per block
        __shared__ float hv_s[Hh];
        int k = blk;
        if (t < Hh) {                      // lane = h: coalesced W1/b1 loads
            float v = (float)k * (3.0f / 127.0f);
            const float HPI = 1.57079632679f;
            float c0 = cosf(HPI * v);
            float c1 = cosf(HPI * (v - 1.0f));
            float c2 = cosf(HPI * (v - 2.0f));
            float s0 = (v < 1.0f) ? c0 * c0 : 0.0f;
            float s1 = (fabsf(v - 1.0f) < 1.0f) ? c1 * c1 : 0.0f;
            float s2 = (v > 1.0f && v < 3.0f) ? c2 * c2 : 0.0f;
            float pre = fmaf(s0, W1[t],
                         fmaf(s1, W1[Hh + t],
                          fmaf(s2, W1[2 * Hh + t], b1[t])));
            hv_s[t] = fmaxf(pre, 0.f);
        }
        __syncthreads();
        if (t < Cc) {                      // lane = c: coalesced W2 rows
            float a0 = 0.f, a1 = 0.f;
            #pragma unroll 4
            for (int h = 0; h < Hh; h += 2) {
                a0 = fmaf(hv_s[h],     W2[h * Cc + t],       a0);
                a1 = fmaf(hv_s[h + 1], W2[(h + 1) * Cc + t], a1);
            }
            ws[UT_OFF + t * KN + k] = a0 + a1;
        }
    } else if (blk < 144) {                // geom4 pack
        int zb = (blk - 128) * 256 + t;
        const float* g = geom + zb * 3;
        reinterpret_cast<float4*>(ws + G4_OFF)[zb] =
            make_float4(g[0], g[1], g[2], 0.f);
    } else if (blk < 148) {                // bias[z]
        __shared__ float red[256];
        int z = blk - 144;
        float s = 0.f;
        #pragma unroll
        for (int rr = 0; rr < 4; ++rr) {
            const float* fr = f + ((z << 10) + rr * 256 + t) * Cc;
            #pragma unroll
            for (int c = 0; c < Cc; ++c) s = fmaf(fr[c], b2[c], s);
        }
        red[t] = s; __syncthreads();
        for (int off = 128; off; off >>= 1) {
            if (t < off) red[t] += red[t + off];
            __syncthreads();
        }
        if (t == 0) ws[BIAS_OFF + z] = red[0];
    } else {                               // colsum[d] = sum_k Wf1[k][d]
        __shared__ float cs_s[240];
        if (t < 240) {
            int d = t % 30, oct = t / 30;
            float c0 = 0.f, c1 = 0.f;
            #pragma unroll 4
            for (int j = 0; j < 128; j += 2) {
                c0 += Wf1[(oct * 128 + j) * 30 + d];
                c1 += Wf1[(oct * 128 + j + 1) * 30 + d];
            }
            cs_s[t] = c0 + c1;
        }
        __syncthreads();
        if (t < 30) {
            float cs = 0.f;
            #pragma unroll
            for (int o = 0; o < 8; ++o) cs += cs_s[o * 30 + t];
            ws[COLSUM_OFF + t] = cs;
        }
    }
}

// ---------------------------------------------------------------------------
// K1: conv + fc1 fold. Block = (z, aq, s): a-range aq*256..+255, b-range
// s*32..+31.  U column per thread via coalesced loads; D-chunk in LDS;
// geometry b-tile in LDS; conv loop = pure LDS+VALU; fc1 partials to pb.
// ---------------------------------------------------------------------------
__global__ __launch_bounds__(256, 2)
void conv_kernel(const float* __restrict__ f,
                 const float* __restrict__ ut,       // ws + UT_OFF
                 const float4* __restrict__ geom4,   // ws + G4_OFF
                 const float* __restrict__ Wf1,
                 float* __restrict__ pb) {           // ws + PB_OFF
    __shared__ float lds_d[32 * DSTR];   // 16896 B (reused as acc staging)
    __shared__ float4 lds_g[32];
    const int bid = blockIdx.x;
    const int t = threadIdx.x;
    const int lane = t & 63;
    const int wv = __builtin_amdgcn_readfirstlane(t >> 6);
    const int z = bid >> 7;
    const int aq = (bid >> 5) & 3;
    const int s = bid & 31;
    const int b0 = s * 32;

    // U column for k = t&127 (lanes consecutive -> coalesced, L2-hot)
    int k = t & 127;
    int rh = __builtin_amdgcn_readfirstlane(t >> 7);   // row half 0/1
    float ur[Cc];
    #pragma unroll
    for (int c = 0; c < Cc; ++c) ur[c] = ut[c * KN + k];

    if (t < 32) lds_g[t] = geom4[(z << 10) + b0 + t];

    // D-chunk rows rh*16..+15 (frow wave-uniform -> one s_load drain per row)
    #pragma unroll 2
    for (int i = 0; i < 16; ++i) {
        int row = rh * 16 + i;
        const float* frow = f + ((z << 10) + b0 + row) * Cc;
        float a0 = 0.f, a1 = 0.f, a2 = 0.f, a3 = 0.f;
        #pragma unroll
        for (int c = 0; c < 20; c += 4) {
            a0 = fmaf(frow[c + 0], ur[c + 0], a0);
            a1 = fmaf(frow[c + 1], ur[c + 1], a1);
            a2 = fmaf(frow[c + 2], ur[c + 2], a2);
            a3 = fmaf(frow[c + 3], ur[c + 3], a3);
        }
        a0 = fmaf(frow[20], ur[20], a0);
        a1 = fmaf(frow[21], ur[21], a1);
        a2 = fmaf(frow[22], ur[22], a2);
        lds_d[row * DSTR + k] = (a0 + a1) + (a2 + a3);
    }
    __syncthreads();

    // conv: thread owns a = aq*256 + t; loop is LDS+VALU only
    float acc = 0.f;
    {
        float4 ga = geom4[(z << 10) + (aq << 8) + t];
        #pragma unroll 8
        for (int bl = 0; bl < 32; ++bl) {
            float4 gb = lds_g[bl];                    // LDS broadcast
            float dx = ga.x - gb.x, dy = ga.y - gb.y, dz = ga.z - gb.z;
            float r = sqrtf(fmaf(dx, dx, fmaf(dy, dy, fmaf(dz, dz, 1e-12f))));
            float mu = fminf(r * MUSCALE, MUCLAMP);
            int m = (int)mu;
            float tt = mu - (float)m;
            const float* row = lds_d + bl * DSTR + m;
            float d0 = row[0];
            float d1 = row[1];
            acc += fmaf(tt, d1 - d0, d0);
        }
    }
    __syncthreads();

    // fc1 fold: 30 partials per block, plain stores (deterministic)
    float* lds_acc = lds_d;
    lds_acc[t] = acc;
    __syncthreads();
    {
        const float4* a4 = reinterpret_cast<const float4*>(lds_acc);
        float4 av = a4[lane];                         // accs for a-local 4*lane..+3
        int kbase = (aq << 8) + (lane << 2);
        #pragma unroll
        for (int i = 0; i < 8; ++i) {
            int d = wv + 4 * i;
            if (d < 30) {
                float sum = av.x * Wf1[(kbase + 0) * 30 + d]
                          + av.y * Wf1[(kbase + 1) * 30 + d]
                          + av.z * Wf1[(kbase + 2) * 30 + d]
                          + av.w * Wf1[(kbase + 3) * 30 + d];
                #pragma unroll
                for (int off = 32; off; off >>= 1) sum += __shfl_down(sum, off);
                if (lane == 0) pb[d * NBLOCKS + bid] = sum * 0.03125f;
            }
        }
    }
}

// ---------------------------------------------------------------------------
// K2: head. Sum 512 partials per (z,d) + bias*colsum term, fc1 relu,
// fc2 relu, fc3. One 256-thread block.
// ---------------------------------------------------------------------------
__global__ __launch_bounds__(256)
void head_kernel(const float* __restrict__ ws,
                 const float* __restrict__ bf1,
                 const float* __restrict__ Wf2, const float* __restrict__ bf2,
                 const float* __restrict__ Wf3, const float* __restrict__ bf3,
                 float* __restrict__ out) {
    __shared__ float tail[448];
    int t = threadIdx.x;
    int p = t >> 1, half = t & 1;
    if (p < 120) {
        int zz = p / 30, d = p % 30;
        const float* pbp = ws + PB_OFF + d * NBLOCKS + zz * 128 + half * 64;
        float s0 = 0.f, s1 = 0.f, s2 = 0.f, s3 = 0.f;
        #pragma unroll
        for (int j = 0; j < 64; j += 4) {
            s0 += pbp[j + 0]; s1 += pbp[j + 1];
            s2 += pbp[j + 2]; s3 += pbp[j + 3];
        }
        tail[t] = (s0 + s1) + (s2 + s3);
    }
    __syncthreads();
    if (t < 120) {
        int zz = t / 30, d = t % 30;
        float x1 = tail[2 * t] + tail[2 * t + 1]
                 + ws[BIAS_OFF + zz] * 0.03125f * ws[COLSUM_OFF + d]
                 + bf1[d];
        tail[256 + t] = fmaxf(x1, 0.f);
    }
    __syncthreads();
    if (t < 40) {
        int zz = t / 10, d = t % 10;
        float sm = bf2[d];
        #pragma unroll
        for (int kk = 0; kk < 30; ++kk)
            sm = fmaf(tail[256 + zz * 30 + kk], Wf2[kk * 10 + d], sm);
        tail[400 + t] = fmaxf(sm, 0.f);
    }
    __syncthreads();
    if (t < 4) {
        float sm = bf3[0];
        #pragma unroll
        for (int kk = 0; kk < 10; ++kk)
            sm = fmaf(tail[400 + t * 10 + kk], Wf3[kk], sm);
        out[t] = sm;
    }
}

extern "C" void kernel_launch(void* const* d_in, const int* in_sizes, int n_in,
                              void* d_out, int out_size, void* d_ws, size_t ws_size,
                              hipStream_t stream) {
    const float* f   = (const float*)d_in[0];
    const float* geo = (const float*)d_in[1];
    const float* W1  = (const float*)d_in[2];
    const float* b1  = (const float*)d_in[3];
    const float* W2  = (const float*)d_in[4];
    const float* b2  = (const float*)d_in[5];
    const float* Wf1 = (const float*)d_in[6];
    const float* bf1 = (const float*)d_in[7];
    const float* Wf2 = (const float*)d_in[8];
    const float* bf2 = (const float*)d_in[9];
    const float* Wf3 = (const float*)d_in[10];
    const float* bf3 = (const float*)d_in[11];
    float* ws  = (float*)d_ws;
    float* out = (float*)d_out;

    hipLaunchKernelGGL(prep_kernel, dim3(149), dim3(256), 0, stream,
                       f, geo, W1, b1, W2, b2, Wf1, ws);
    hipLaunchKernelGGL(conv_kernel, dim3(NBLOCKS), dim3(256), 0, stream,
                       f, ws + UT_OFF,
                       reinterpret_cast<const float4*>(ws + G4_OFF),
                       Wf1, ws + PB_OFF);
    hipLaunchKernelGGL(head_kernel, dim3(1), dim3(256), 0, stream,
                       ws, bf1, Wf2, bf2, Wf3, bf3, out);
}

// Round 11
// 26.650 us; speedup vs baseline: 5.6106x; 1.1838x over previous
//
#include <hip/hip_runtime.h>

#define Nn 1024
#define Cc 23
#define Hh 100
#define KN 128                 // knots over v=r/1.5 in [0,3], 127 cells
#define DSTR 132               // lds_d row stride (128 + pad)
#define MUSCALE 28.2222222f    // 127/4.5  (mu = r * MUSCALE)
#define MUCLAMP 126.999f
#define NB 1024                // conv blocks: z(4) x aq(4) x s(64)

// ws float offsets
#define UT_OFF     0           // U transposed [23][128] = 2944
#define WF1T_OFF   4096        // Wf1^T / 32  [30][1024] = 30720
#define G4_OFF     34816       // [4096][4] = 16384
#define BIAS_OFF   51200       // [4]
#define COLSUM_OFF 51204       // [30]
#define PB_OFF     51264       // [30][1024] fc1 partials = 30720

__device__ __forceinline__ float rdlane(float v, int l) {
    return __int_as_float(__builtin_amdgcn_readlane(__float_as_int(v), l));
}

// ---------------------------------------------------------------------------
// K0: 179 blocks.
//  0..127  : U_T[c][k] for one knot k (W2 LDS-staged, coalesced)
//  128..143: geom4 pack
//  144..147: bias[z]
//  148     : colsum[d] = sum_k Wf1[k][d]
//  149..178: Wf1T[d][k] = Wf1[k][d] / 32 (coalesced writes)
// ---------------------------------------------------------------------------
__global__ __launch_bounds__(256)
void prep_kernel(const float* __restrict__ f,
                 const float* __restrict__ geom,
                 const float* __restrict__ W1,
                 const float* __restrict__ b1,
                 const float* __restrict__ W2,
                 const float* __restrict__ b2,
                 const float* __restrict__ Wf1,
                 float* __restrict__ ws) {
    int blk = blockIdx.x;
    int t = threadIdx.x;
    if (blk < 128) {
        __shared__ float w2s[Hh * Cc];     // 9200 B
        __shared__ float hv_s[Hh];
        int k = blk;
        for (int j = t; j < Hh * Cc; j += 256) w2s[j] = W2[j];
        if (t < Hh) {                      // lane = h: coalesced W1/b1
            float v = (float)k * (3.0f / 127.0f);
            const float HPI = 1.57079632679f;
            float c0 = cosf(HPI * v);
            float c1 = cosf(HPI * (v - 1.0f));
            float c2 = cosf(HPI * (v - 2.0f));
            float s0 = (v < 1.0f) ? c0 * c0 : 0.0f;
            float s1 = (fabsf(v - 1.0f) < 1.0f) ? c1 * c1 : 0.0f;
            float s2 = (v > 1.0f && v < 3.0f) ? c2 * c2 : 0.0f;
            float pre = fmaf(s0, W1[t],
                         fmaf(s1, W1[Hh + t],
                          fmaf(s2, W1[2 * Hh + t], b1[t])));
            hv_s[t] = fmaxf(pre, 0.f);
        }
        __syncthreads();
        if (t < Cc) {
            float a0 = 0.f, a1 = 0.f;
            #pragma unroll 4
            for (int h = 0; h < Hh; h += 2) {
                a0 = fmaf(hv_s[h],     w2s[h * Cc + t],       a0);
                a1 = fmaf(hv_s[h + 1], w2s[(h + 1) * Cc + t], a1);
            }
            ws[UT_OFF + t * KN + k] = a0 + a1;
        }
    } else if (blk < 144) {                // geom4 pack
        int zb = (blk - 128) * 256 + t;
        const float* g = geom + zb * 3;
        reinterpret_cast<float4*>(ws + G4_OFF)[zb] =
            make_float4(g[0], g[1], g[2], 0.f);
    } else if (blk < 148) {                // bias[z]
        __shared__ float red[256];
        int z = blk - 144;
        float s = 0.f;
        #pragma unroll
        for (int rr = 0; rr < 4; ++rr) {
            const float* fr = f + ((z << 10) + rr * 256 + t) * Cc;
            #pragma unroll
            for (int c = 0; c < Cc; ++c) s = fmaf(fr[c], b2[c], s);
        }
        red[t] = s; __syncthreads();
        for (int off = 128; off; off >>= 1) {
            if (t < off) red[t] += red[t + off];
            __syncthreads();
        }
        if (t == 0) ws[BIAS_OFF + z] = red[0];
    } else if (blk == 148) {               // colsum
        __shared__ float cs_s[240];
        if (t < 240) {
            int d = t % 30, oct = t / 30;
            float c0 = 0.f, c1 = 0.f;
            #pragma unroll 4
            for (int j = 0; j < 128; j += 2) {
                c0 += Wf1[(oct * 128 + j) * 30 + d];
                c1 += Wf1[(oct * 128 + j + 1) * 30 + d];
            }
            cs_s[t] = c0 + c1;
        }
        __syncthreads();
        if (t < 30) {
            float cs = 0.f;
            #pragma unroll
            for (int o = 0; o < 8; ++o) cs += cs_s[o * 30 + t];
            ws[COLSUM_OFF + t] = cs;
        }
    } else {                               // Wf1T: one d per block
        int d = blk - 149;
        #pragma unroll
        for (int j = 0; j < 4; ++j) {
            int k = j * 256 + t;
            ws[WF1T_OFF + d * Nn + k] = Wf1[k * 30 + d] * 0.03125f;
        }
    }
}

// ---------------------------------------------------------------------------
// K1: conv + fc1 fold. 1024 blocks x 256 thr. Block (z, aq, s): a-range
// aq*256..+255, b-range s*16..+15.
//  - U column (23) via coalesced global loads (lane = k)
//  - f-chunk in per-lane VGPRs; D-build broadcasts via v_readlane (no s_load,
//    no LDS) -> lds_d[16][DSTR]
//  - geometry b-tile in 1 VGPR, broadcast via v_readlane
//  - conv lerp-gather from lds_d
//  - fold through Wf1T (coalesced float4) -> pb[d][bid]
// ---------------------------------------------------------------------------
__global__ __launch_bounds__(256, 4)
void conv_kernel(const float* __restrict__ f,
                 const float* __restrict__ geom,
                 const float* __restrict__ ut,       // ws + UT_OFF
                 const float4* __restrict__ geom4,   // ws + G4_OFF
                 const float4* __restrict__ wf1t4,   // ws + WF1T_OFF
                 float* __restrict__ pb) {           // ws + PB_OFF
    __shared__ float lds_d[16 * DSTR];   // 8448 B (aliased as acc staging)
    const int bid = blockIdx.x;
    const int t = threadIdx.x;
    const int lane = t & 63;
    const int wv = __builtin_amdgcn_readfirstlane(t >> 6);
    const int z = bid >> 8;
    const int aq = (bid >> 6) & 3;
    const int s = bid & 63;
    const int b0 = s * 16;
    const int k = t & 127;
    const int rh = __builtin_amdgcn_readfirstlane(t >> 7);   // row half 0/1

    // staging loads (all coalesced / per-lane)
    float ur[Cc];
    #pragma unroll
    for (int c = 0; c < Cc; ++c) ur[c] = ut[c * KN + k];
    float fr[3];                            // wave's 8 rows x 23 f values
    {
        int base = ((z << 10) + b0 + rh * 8) * Cc;
        #pragma unroll
        for (int j = 0; j < 3; ++j) {
            int off = j * 64 + lane;
            if (off > 183) off = 183;
            fr[j] = f[base + off];
        }
    }
    float gr;                               // 16 b-geometries (48 floats)
    {
        int off = lane < 48 ? lane : 47;
        gr = geom[((z << 10) + b0) * 3 + off];
    }
    float4 ga = geom4[(z << 10) + (aq << 8) + t];

    // D-build: 8 rows per wave-half, f broadcast via readlane
    #pragma unroll
    for (int r = 0; r < 8; ++r) {
        float a0 = 0.f, a1 = 0.f, a2 = 0.f, a3 = 0.f;
        #pragma unroll
        for (int c = 0; c < 20; c += 4) {
            a0 = fmaf(rdlane(fr[(r * Cc + c + 0) >> 6], (r * Cc + c + 0) & 63), ur[c + 0], a0);
            a1 = fmaf(rdlane(fr[(r * Cc + c + 1) >> 6], (r * Cc + c + 1) & 63), ur[c + 1], a1);
            a2 = fmaf(rdlane(fr[(r * Cc + c + 2) >> 6], (r * Cc + c + 2) & 63), ur[c + 2], a2);
            a3 = fmaf(rdlane(fr[(r * Cc + c + 3) >> 6], (r * Cc + c + 3) & 63), ur[c + 3], a3);
        }
        a0 = fmaf(rdlane(fr[(r * Cc + 20) >> 6], (r * Cc + 20) & 63), ur[20], a0);
        a1 = fmaf(rdlane(fr[(r * Cc + 21) >> 6], (r * Cc + 21) & 63), ur[21], a1);
        a2 = fmaf(rdlane(fr[(r * Cc + 22) >> 6], (r * Cc + 22) & 63), ur[22], a2);
        lds_d[(rh * 8 + r) * DSTR + k] = (a0 + a1) + (a2 + a3);
    }
    __syncthreads();

    // conv: thread owns a = aq*256 + t; geometry broadcast via readlane
    float acc = 0.f;
    #pragma unroll
    for (int bl = 0; bl < 16; ++bl) {
        float dx = ga.x - rdlane(gr, bl * 3 + 0);
        float dy = ga.y - rdlane(gr, bl * 3 + 1);
        float dz = ga.z - rdlane(gr, bl * 3 + 2);
        float r = sqrtf(fmaf(dx, dx, fmaf(dy, dy, fmaf(dz, dz, 1e-12f))));
        float mu = fminf(r * MUSCALE, MUCLAMP);
        int m = (int)mu;
        float tt = mu - (float)m;
        const float* row = lds_d + bl * DSTR + m;
        float d0 = row[0];
        float d1 = row[1];
        acc += fmaf(tt, d1 - d0, d0);
    }
    __syncthreads();

    // fold: acc -> 30 per-block fc1 partials via Wf1T (coalesced float4)
    lds_d[t] = acc;
    __syncthreads();
    {
        const float4* a4 = reinterpret_cast<const float4*>(lds_d);
        float4 av = a4[lane];                      // accs for a-local 4*lane..+3
        #pragma unroll
        for (int i = 0; i < 8; ++i) {
            int d = wv + 4 * i;
            if (d < 30) {
                float4 w = wf1t4[d * 256 + (aq << 6) + lane];
                float sum = av.x * w.x + av.y * w.y + av.z * w.z + av.w * w.w;
                #pragma unroll
                for (int off = 32; off; off >>= 1) sum += __shfl_down(sum, off);
                if (lane == 0) pb[d * NB + bid] = sum;
            }
        }
    }
}

// ---------------------------------------------------------------------------
// K2: head. x1[z][d] = relu( sum_{256 blocks} pb + bias_z*colsum_d/32 + bf1 ),
// fc2 relu, fc3. One 256-thread block.
// ---------------------------------------------------------------------------
__global__ __launch_bounds__(256)
void head_kernel(const float* __restrict__ ws,
                 const float* __restrict__ bf1,
                 const float* __restrict__ Wf2, const float* __restrict__ bf2,
                 const float* __restrict__ Wf3, const float* __restrict__ bf3,
                 float* __restrict__ out) {
    __shared__ float tail[448];
    int t = threadIdx.x;
    int p = t >> 1, half = t & 1;
    if (p < 120) {
        int zz = p / 30, d = p % 30;
        const float4* pbp = reinterpret_cast<const float4*>(
            ws + PB_OFF + d * NB + zz * 256 + half * 128);
        float s0 = 0.f, s1 = 0.f, s2 = 0.f, s3 = 0.f;
        #pragma unroll 8
        for (int j = 0; j < 32; ++j) {
            float4 v = pbp[j];
            s0 += v.x; s1 += v.y; s2 += v.z; s3 += v.w;
        }
        tail[t] = (s0 + s1) + (s2 + s3);
    }
    __syncthreads();
    if (t < 120) {
        int zz = t / 30, d = t % 30;
        float x1 = tail[2 * t] + tail[2 * t + 1]
                 + ws[BIAS_OFF + zz] * 0.03125f * ws[COLSUM_OFF + d]
                 + bf1[d];
        tail[256 + t] = fmaxf(x1, 0.f);
    }
    __syncthreads();
    if (t < 40) {
        int zz = t / 10, d = t % 10;
        float sm = bf2[d];
        #pragma unroll
        for (int kk = 0; kk < 30; ++kk)
            sm = fmaf(tail[256 + zz * 30 + kk], Wf2[kk * 10 + d], sm);
        tail[400 + t] = fmaxf(sm, 0.f);
    }
    __syncthreads();
    if (t < 4) {
        float sm = bf3[0];
        #pragma unroll
        for (int kk = 0; kk < 10; ++kk)
            sm = fmaf(tail[400 + t * 10 + kk], Wf3[kk], sm);
        out[t] = sm;
    }
}

extern "C" void kernel_launch(void* const* d_in, const int* in_sizes, int n_in,
                              void* d_out, int out_size, void* d_ws, size_t ws_size,
                              hipStream_t stream) {
    const float* f   = (const float*)d_in[0];
    const float* geo = (const float*)d_in[1];
    const float* W1  = (const float*)d_in[2];
    const float* b1  = (const float*)d_in[3];
    const float* W2  = (const float*)d_in[4];
    const float* b2  = (const float*)d_in[5];
    const float* Wf1 = (const float*)d_in[6];
    const float* bf1 = (const float*)d_in[7];
    const float* Wf2 = (const float*)d_in[8];
    const float* bf2 = (const float*)d_in[9];
    const float* Wf3 = (const float*)d_in[10];
    const float* bf3 = (const float*)d_in[11];
    float* ws  = (float*)d_ws;
    float* out = (float*)d_out;

    hipLaunchKernelGGL(prep_kernel, dim3(179), dim3(256), 0, stream,
                       f, geo, W1, b1, W2, b2, Wf1, ws);
    hipLaunchKernelGGL(conv_kernel, dim3(NB), dim3(256), 0, stream,
                       f, geo, ws + UT_OFF,
                       reinterpret_cast<const float4*>(ws + G4_OFF),
                       reinterpret_cast<const float4*>(ws + WF1T_OFF),
                       ws + PB_OFF);
    hipLaunchKernelGGL(head_kernel, dim3(1), dim3(256), 0, stream,
                       ws, bf1, Wf2, bf2, Wf3, bf3, out);
}

// Round 12
// 26.100 us; speedup vs baseline: 5.7287x; 1.0210x over previous
//
#include <hip/hip_runtime.h>

#define Nn 1024
#define Cc 23
#define Hh 100
#define KN 128                 // knots over v=r/1.5 in [0,3], 127 cells
#define DSTR 132               // lds_d row stride (128 + pad)
#define MUSCALE 28.2222222f    // 127/4.5  (mu = r * MUSCALE)
#define MUCLAMP 126.999f
#define NB 1024                // conv blocks: z(4) x aq(4) x s(64)

// ws float offsets
#define UT_OFF     0           // U transposed [23][128] = 2944
#define WF1T_OFF   4096        // Wf1^T / 32  [30][1024] = 30720
#define G4_OFF     34816       // [4096][4] = 16384
#define BIAS_OFF   51200       // [4]
#define COLSUM_OFF 51204       // [30]
#define D_OFF      51264       // D[4096][128] = 524288
#define PB_OFF     575552      // [30][1024] fc1 partials = 30720
#define X1PRE_OFF  606272      // [30][4]

__device__ __forceinline__ float rdlane(float v, int l) {
    return __int_as_float(__builtin_amdgcn_readlane(__float_as_int(v), l));
}

// ---------------------------------------------------------------------------
// K0: 179 blocks (unchanged from R10).
//  0..127: U_T[c][k]; 128..143: geom4; 144..147: bias; 148: colsum;
//  149..178: Wf1T[d][k] = Wf1[k][d]/32
// ---------------------------------------------------------------------------
__global__ __launch_bounds__(256)
void prep_kernel(const float* __restrict__ f,
                 const float* __restrict__ geom,
                 const float* __restrict__ W1,
                 const float* __restrict__ b1,
                 const float* __restrict__ W2,
                 const float* __restrict__ b2,
                 const float* __restrict__ Wf1,
                 float* __restrict__ ws) {
    int blk = blockIdx.x;
    int t = threadIdx.x;
    if (blk < 128) {
        __shared__ float w2s[Hh * Cc];
        __shared__ float hv_s[Hh];
        int k = blk;
        for (int j = t; j < Hh * Cc; j += 256) w2s[j] = W2[j];
        if (t < Hh) {
            float v = (float)k * (3.0f / 127.0f);
            const float HPI = 1.57079632679f;
            float c0 = cosf(HPI * v);
            float c1 = cosf(HPI * (v - 1.0f));
            float c2 = cosf(HPI * (v - 2.0f));
            float s0 = (v < 1.0f) ? c0 * c0 : 0.0f;
            float s1 = (fabsf(v - 1.0f) < 1.0f) ? c1 * c1 : 0.0f;
            float s2 = (v > 1.0f && v < 3.0f) ? c2 * c2 : 0.0f;
            float pre = fmaf(s0, W1[t],
                         fmaf(s1, W1[Hh + t],
                          fmaf(s2, W1[2 * Hh + t], b1[t])));
            hv_s[t] = fmaxf(pre, 0.f);
        }
        __syncthreads();
        if (t < Cc) {
            float a0 = 0.f, a1 = 0.f;
            #pragma unroll 4
            for (int h = 0; h < Hh; h += 2) {
                a0 = fmaf(hv_s[h],     w2s[h * Cc + t],       a0);
                a1 = fmaf(hv_s[h + 1], w2s[(h + 1) * Cc + t], a1);
            }
            ws[UT_OFF + t * KN + k] = a0 + a1;
        }
    } else if (blk < 144) {
        int zb = (blk - 128) * 256 + t;
        const float* g = geom + zb * 3;
        reinterpret_cast<float4*>(ws + G4_OFF)[zb] =
            make_float4(g[0], g[1], g[2], 0.f);
    } else if (blk < 148) {
        __shared__ float red[256];
        int z = blk - 144;
        float s = 0.f;
        #pragma unroll
        for (int rr = 0; rr < 4; ++rr) {
            const float* fr = f + ((z << 10) + rr * 256 + t) * Cc;
            #pragma unroll
            for (int c = 0; c < Cc; ++c) s = fmaf(fr[c], b2[c], s);
        }
        red[t] = s; __syncthreads();
        for (int off = 128; off; off >>= 1) {
            if (t < off) red[t] += red[t + off];
            __syncthreads();
        }
        if (t == 0) ws[BIAS_OFF + z] = red[0];
    } else if (blk == 148) {
        __shared__ float cs_s[240];
        if (t < 240) {
            int d = t % 30, oct = t / 30;
            float c0 = 0.f, c1 = 0.f;
            #pragma unroll 4
            for (int j = 0; j < 128; j += 2) {
                c0 += Wf1[(oct * 128 + j) * 30 + d];
                c1 += Wf1[(oct * 128 + j + 1) * 30 + d];
            }
            cs_s[t] = c0 + c1;
        }
        __syncthreads();
        if (t < 30) {
            float cs = 0.f;
            #pragma unroll
            for (int o = 0; o < 8; ++o) cs += cs_s[o * 30 + t];
            ws[COLSUM_OFF + t] = cs;
        }
    } else {
        int d = blk - 149;
        #pragma unroll
        for (int j = 0; j < 4; ++j) {
            int k = j * 256 + t;
            ws[WF1T_OFF + d * Nn + k] = Wf1[k * 30 + d] * 0.03125f;
        }
    }
}

// ---------------------------------------------------------------------------
// K1: dgemm — D[row][k] = sum_c UT[c][k] * f[row][c]. 512 blocks x 256 thr,
// 8 rows/block (4 per half). Coalesced UT loads; f broadcast via readlane.
// Every f row touched exactly once (no redundancy).
// ---------------------------------------------------------------------------
__global__ __launch_bounds__(256)
void dgemm_kernel(const float* __restrict__ f,
                  const float* __restrict__ ut,    // ws + UT_OFF
                  float* __restrict__ D) {         // ws + D_OFF
    const int bid = blockIdx.x;
    const int t = threadIdx.x;
    const int lane = t & 63;
    const int k = t & 127;
    const int rh = __builtin_amdgcn_readfirstlane(t >> 7);   // 0/1
    float ur[Cc];
    #pragma unroll
    for (int c = 0; c < Cc; ++c) ur[c] = ut[c * KN + k];
    const int row0 = bid * 8 + rh * 4;
    float fr[2];                          // 4 rows x 23 = 92 floats per half
    {
        int base = row0 * Cc;
        #pragma unroll
        for (int j = 0; j < 2; ++j) {
            int off = j * 64 + lane;
            if (off > 91) off = 91;
            fr[j] = f[base + off];
        }
    }
    #pragma unroll
    for (int r = 0; r < 4; ++r) {
        float a0 = 0.f, a1 = 0.f, a2 = 0.f, a3 = 0.f;
        #pragma unroll
        for (int c = 0; c < 20; c += 4) {
            a0 = fmaf(rdlane(fr[(r * Cc + c + 0) >> 6], (r * Cc + c + 0) & 63), ur[c + 0], a0);
            a1 = fmaf(rdlane(fr[(r * Cc + c + 1) >> 6], (r * Cc + c + 1) & 63), ur[c + 1], a1);
            a2 = fmaf(rdlane(fr[(r * Cc + c + 2) >> 6], (r * Cc + c + 2) & 63), ur[c + 2], a2);
            a3 = fmaf(rdlane(fr[(r * Cc + c + 3) >> 6], (r * Cc + c + 3) & 63), ur[c + 3], a3);
        }
        a0 = fmaf(rdlane(fr[(r * Cc + 20) >> 6], (r * Cc + 20) & 63), ur[20], a0);
        a1 = fmaf(rdlane(fr[(r * Cc + 21) >> 6], (r * Cc + 21) & 63), ur[21], a1);
        a2 = fmaf(rdlane(fr[(r * Cc + 22) >> 6], (r * Cc + 22) & 63), ur[22], a2);
        D[(row0 + r) * KN + k] = (a0 + a1) + (a2 + a3);
    }
}

// ---------------------------------------------------------------------------
// K2: conv + fc1 fold. 1024 blocks x 256 thr, 4/CU. Block (z, aq, s).
// D-tile staged from global (coalesced float4); edges pure LDS+VALU;
// fold through Wf1T -> pb[d][bid].
// ---------------------------------------------------------------------------
__global__ __launch_bounds__(256, 4)
void conv_kernel(const float* __restrict__ geom,
                 const float* __restrict__ Dg,       // ws + D_OFF
                 const float4* __restrict__ geom4,   // ws + G4_OFF
                 const float4* __restrict__ wf1t4,   // ws + WF1T_OFF
                 float* __restrict__ pb) {           // ws + PB_OFF
    __shared__ float lds_d[16 * DSTR];   // 8448 B (aliased as acc staging)
    const int bid = blockIdx.x;
    const int t = threadIdx.x;
    const int lane = t & 63;
    const int wv = __builtin_amdgcn_readfirstlane(t >> 6);
    const int z = bid >> 8;
    const int aq = (bid >> 6) & 3;
    const int s = bid & 63;
    const int b0 = s * 16;

    // stage D-tile: 16 rows x 128 k = 512 float4, 2 rounds, coalesced
    {
        const float4* src = reinterpret_cast<const float4*>(Dg + ((z << 10) + b0) * KN);
        #pragma unroll
        for (int j = t; j < 512; j += 256) {
            int row = j >> 5, k4 = j & 31;
            reinterpret_cast<float4*>(lds_d)[row * 33 + k4] = src[j];
        }
    }
    float gr;                               // 16 b-geometries (48 floats)
    {
        int off = lane < 48 ? lane : 47;
        gr = geom[((z << 10) + b0) * 3 + off];
    }
    float4 ga = geom4[(z << 10) + (aq << 8) + t];
    __syncthreads();

    // conv: thread owns a = aq*256 + t
    float acc = 0.f;
    #pragma unroll
    for (int bl = 0; bl < 16; ++bl) {
        float dx = ga.x - rdlane(gr, bl * 3 + 0);
        float dy = ga.y - rdlane(gr, bl * 3 + 1);
        float dz = ga.z - rdlane(gr, bl * 3 + 2);
        float r = sqrtf(fmaf(dx, dx, fmaf(dy, dy, fmaf(dz, dz, 1e-12f))));
        float mu = fminf(r * MUSCALE, MUCLAMP);
        int m = (int)mu;
        float tt = mu - (float)m;
        const float* row = lds_d + bl * DSTR + m;
        float d0 = row[0];
        float d1 = row[1];
        acc += fmaf(tt, d1 - d0, d0);
    }
    __syncthreads();

    // fold: acc -> 30 per-block fc1 partials via Wf1T (coalesced float4)
    lds_d[t] = acc;
    __syncthreads();
    {
        const float4* a4 = reinterpret_cast<const float4*>(lds_d);
        float4 av = a4[lane];                      // accs for a-local 4*lane..+3
        #pragma unroll
        for (int i = 0; i < 8; ++i) {
            int d = wv + 4 * i;
            if (d < 30) {
                float4 w = wf1t4[d * 256 + (aq << 6) + lane];
                float sum = av.x * w.x + av.y * w.y + av.z * w.z + av.w * w.w;
                #pragma unroll
                for (int off = 32; off; off >>= 1) sum += __shfl_down(sum, off);
                if (lane == 0) pb[d * NB + bid] = sum;
            }
        }
    }
}

// ---------------------------------------------------------------------------
// K3: head1 — 30 blocks (one d each). One float4/thread; wave w owns z=w;
// shfl-reduce -> x1pre[d][z] (raw sum, bias/relu applied in fc23).
// ---------------------------------------------------------------------------
__global__ __launch_bounds__(256)
void head1_kernel(const float* __restrict__ pb,     // ws + PB_OFF
                  float* __restrict__ x1pre) {      // ws + X1PRE_OFF
    int d = blockIdx.x;
    int t = threadIdx.x;
    const float4* p4 = reinterpret_cast<const float4*>(pb + d * NB);
    float4 v = p4[t];
    float s = (v.x + v.y) + (v.z + v.w);
    #pragma unroll
    for (int off = 32; off; off >>= 1) s += __shfl_down(s, off);
    if ((t & 63) == 0) x1pre[d * 4 + (t >> 6)] = s;
}

// ---------------------------------------------------------------------------
// K4: fc23 — x1 = relu(x1pre + bias*colsum/32 + bf1), fc2 relu, fc3.
// ---------------------------------------------------------------------------
__global__ __launch_bounds__(128)
void fc23_kernel(const float* __restrict__ ws,
                 const float* __restrict__ bf1,
                 const float* __restrict__ Wf2, const float* __restrict__ bf2,
                 const float* __restrict__ Wf3, const float* __restrict__ bf3,
                 float* __restrict__ out) {
    __shared__ float x1s[120];
    __shared__ float x2s[40];
    int t = threadIdx.x;
    if (t < 120) {
        int z = t / 30, d = t % 30;
        float x1 = ws[X1PRE_OFF + d * 4 + z]
                 + ws[BIAS_OFF + z] * 0.03125f * ws[COLSUM_OFF + d]
                 + bf1[d];
        x1s[t] = fmaxf(x1, 0.f);
    }
    __syncthreads();
    if (t < 40) {
        int z = t / 10, d = t % 10;
        float sm = bf2[d];
        #pragma unroll
        for (int kk = 0; kk < 30; ++kk)
            sm = fmaf(x1s[z * 30 + kk], Wf2[kk * 10 + d], sm);
        x2s[t] = fmaxf(sm, 0.f);
    }
    __syncthreads();
    if (t < 4) {
        float sm = bf3[0];
        #pragma unroll
        for (int kk = 0; kk < 10; ++kk)
            sm = fmaf(x2s[t * 10 + kk], Wf3[kk], sm);
        out[t] = sm;
    }
}

extern "C" void kernel_launch(void* const* d_in, const int* in_sizes, int n_in,
                              void* d_out, int out_size, void* d_ws, size_t ws_size,
                              hipStream_t stream) {
    const float* f   = (const float*)d_in[0];
    const float* geo = (const float*)d_in[1];
    const float* W1  = (const float*)d_in[2];
    const float* b1  = (const float*)d_in[3];
    const float* W2  = (const float*)d_in[4];
    const float* b2  = (const float*)d_in[5];
    const float* Wf1 = (const float*)d_in[6];
    const float* bf1 = (const float*)d_in[7];
    const float* Wf2 = (const float*)d_in[8];
    const float* bf2 = (const float*)d_in[9];
    const float* Wf3 = (const float*)d_in[10];
    const float* bf3 = (const float*)d_in[11];
    float* ws  = (float*)d_ws;
    float* out = (float*)d_out;

    hipLaunchKernelGGL(prep_kernel, dim3(179), dim3(256), 0, stream,
                       f, geo, W1, b1, W2, b2, Wf1, ws);
    hipLaunchKernelGGL(dgemm_kernel, dim3(512), dim3(256), 0, stream,
                       f, ws + UT_OFF, ws + D_OFF);
    hipLaunchKernelGGL(conv_kernel, dim3(NB), dim3(256), 0, stream,
                       geo, ws + D_OFF,
                       reinterpret_cast<const float4*>(ws + G4_OFF),
                       reinterpret_cast<const float4*>(ws + WF1T_OFF),
                       ws + PB_OFF);
    hipLaunchKernelGGL(head1_kernel, dim3(30), dim3(256), 0, stream,
                       ws + PB_OFF, ws + X1PRE_OFF);
    hipLaunchKernelGGL(fc23_kernel, dim3(1), dim3(128), 0, stream,
                       ws, bf1, Wf2, bf2, Wf3, bf3, out);
}